// Round 6
// baseline (119.216 us; speedup 1.0000x reference)
//
#include <hip/hip_runtime.h>

#define NN 4096
#define DD 512
#define CP 128          // classes padded to 128 (pad classes: cnt=0, G=0 -> vanish)
#define MT 16           // k2 M-tile rows per block
#define NB2 (NN / MT)   // 256 blocks

// ws float-word offsets
#define NEG_OFF   0
#define DONE_OFF  1
#define D_OFF     64
#define INVI_OFF  (64 + NN)
#define INVT_OFF  (64 + 2*NN)
#define CNTF_OFF  (64 + 3*NN)
#define TXB_OFF_W 16384                      // bf16 txtN [NN][DD] starts here
#define GB_OFF_W  (TXB_OFF_W + NN*DD/2)      // bf16 G [CP][DD]

typedef __attribute__((ext_vector_type(8))) short bf16x8;
typedef __attribute__((ext_vector_type(4))) float f32x4;

static __device__ inline unsigned short f2bf(float f) {
    unsigned int u = __float_as_uint(f);
    unsigned int r = u + 0x7fffu + ((u >> 16) & 1u);   // round-to-nearest-even
    return (unsigned short)(r >> 16);
}

// K1: wave-per-row norms + pos-dot; writes txtN as bf16. No atomics.
__global__ __launch_bounds__(256) void k1_rows(const float* __restrict__ img,
                                               const float* __restrict__ txt,
                                               float* __restrict__ ws) {
    int w = threadIdx.x >> 6, l = threadIdx.x & 63;
    int row = blockIdx.x * 4 + w;
    const float4* i4 = (const float4*)(img + (size_t)row * DD);
    const float4* t4 = (const float4*)(txt + (size_t)row * DD);
    float4 a0 = i4[l], a1 = i4[l + 64];
    float4 b0 = t4[l], b1 = t4[l + 64];
    float ssi = a0.x*a0.x + a0.y*a0.y + a0.z*a0.z + a0.w*a0.w
              + a1.x*a1.x + a1.y*a1.y + a1.z*a1.z + a1.w*a1.w;
    float sst = b0.x*b0.x + b0.y*b0.y + b0.z*b0.z + b0.w*b0.w
              + b1.x*b1.x + b1.y*b1.y + b1.z*b1.z + b1.w*b1.w;
    float dot = a0.x*b0.x + a0.y*b0.y + a0.z*b0.z + a0.w*b0.w
              + a1.x*b1.x + a1.y*b1.y + a1.z*b1.z + a1.w*b1.w;
    #pragma unroll
    for (int o = 32; o >= 1; o >>= 1) {
        ssi += __shfl_xor(ssi, o);
        sst += __shfl_xor(sst, o);
        dot += __shfl_xor(dot, o);
    }
    float inv_t = rsqrtf(sst);
    unsigned short* txb = (unsigned short*)(ws + TXB_OFF_W);
    ushort4 s0, s1;
    s0.x = f2bf(b0.x * inv_t); s0.y = f2bf(b0.y * inv_t);
    s0.z = f2bf(b0.z * inv_t); s0.w = f2bf(b0.w * inv_t);
    s1.x = f2bf(b1.x * inv_t); s1.y = f2bf(b1.y * inv_t);
    s1.z = f2bf(b1.z * inv_t); s1.w = f2bf(b1.w * inv_t);
    *(ushort4*)(txb + (size_t)row * DD + 4 * l)       = s0;
    *(ushort4*)(txb + (size_t)row * DD + 256 + 4 * l) = s1;
    if (l == 0) {
        float inv_i = rsqrtf(ssi);
        ws[D_OFF + row]    = dot * inv_i * inv_t;
        ws[INVI_OFF + row] = inv_i;
        ws[INVT_OFF + row] = inv_t;
    }
    if (blockIdx.x == 0 && threadIdx.x == 0) {
        ws[NEG_OFF] = 0.0f;
        ((int*)ws)[DONE_OFF] = 0;
    }
}

// K1b: one block per class; ballot-scan labels, gather member rows, write G bf16.
__global__ __launch_bounds__(512) void k1b_gather(const float* __restrict__ img,
                                                  const int* __restrict__ labels,
                                                  float* __restrict__ ws) {
    __shared__ int list[256];
    __shared__ int scnt;
    __shared__ float4 pg[4][128];
    int c = blockIdx.x;
    int t = threadIdx.x;
    if (t < 64) {   // wave 0 fully active
        int cnt = 0;
        for (int i = 0; i < NN / 64; ++i) {
            int lab = labels[i * 64 + t];
            unsigned long long m = __ballot(lab == c);
            int pre = (int)__popcll(m & ((1ull << t) - 1ull));
            if (lab == c) {
                int p = cnt + pre;
                if (p < 256) list[p] = i * 64 + t;
            }
            cnt += (int)__popcll(m);
        }
        if (t == 0) scnt = cnt < 256 ? cnt : 256;
    }
    __syncthreads();
    int n   = scnt;
    int sub = t >> 7;
    int l   = t & 127;
    const float* invi  = ws + INVI_OFF;
    const float4* img4 = (const float4*)img;
    float ax = 0.f, ay = 0.f, az = 0.f, aw = 0.f;
    for (int s = sub; s < n; s += 4) {
        int j = list[s];
        float wv = invi[j];
        float4 v = img4[(size_t)j * 128 + l];
        ax += v.x * wv; ay += v.y * wv; az += v.z * wv; aw += v.w * wv;
    }
    float4 mine; mine.x = ax; mine.y = ay; mine.z = az; mine.w = aw;
    pg[sub][l] = mine;
    __syncthreads();
    if (sub == 0) {
        float4 r0 = pg[0][l], r1 = pg[1][l], r2 = pg[2][l], r3 = pg[3][l];
        float rx = r0.x + r1.x + r2.x + r3.x;
        float ry = r0.y + r1.y + r2.y + r3.y;
        float rz = r0.z + r1.z + r2.z + r3.z;
        float rw = r0.w + r1.w + r2.w + r3.w;
        unsigned short* gbf = (unsigned short*)(ws + GB_OFF_W);
        ushort4 o;
        o.x = f2bf(rx); o.y = f2bf(ry); o.z = f2bf(rz); o.w = f2bf(rw);
        *(ushort4*)(gbf + (size_t)c * DD + 4 * l) = o;
        if (l == 0) ws[CNTF_OFF + c] = (float)n;
    }
}

// K2: MFMA GEMM R[4096x128] = txtN_bf16 @ G_bf16^T. 256 blocks (MT=16 rows), 4 waves.
// A (16KB) staged once; B (G, 128KB) staged in two 64KB K-halves, loads for half 1
// issued before compute of half 0 (latency hidden). 3 barriers total in the GEMM.
// XOR-swizzled LDS (byte ^= (row&7)<<4) -> conflict-free ds_read_b128.
__global__ __launch_bounds__(256) void k2_neg(float* __restrict__ ws,
                                              float* __restrict__ out) {
    __shared__ __align__(16) unsigned char As[MT * DD * 2];    // 16 KB
    __shared__ __align__(16) unsigned char Bs[CP * 256 * 2];   // 64 KB (one K-half)
    __shared__ float cnts[CP];
    __shared__ float part[4][MT];
    __shared__ float Ss[MT];
    __shared__ float wred[4];
    __shared__ float sneg;
    __shared__ int   sdone;
    int t = threadIdx.x;
    int w = t >> 6, l = t & 63;
    int row0 = blockIdx.x * MT;
    if (t < CP) cnts[t] = ws[CNTF_OFF + t];
    const unsigned short* txb = (const unsigned short*)(ws + TXB_OFF_W);
    const int4* gB = (const int4*)(ws + GB_OFF_W);              // G as int4: idx = c*64 + h*32 + o
    const int4* gA = (const int4*)(txb + (size_t)row0 * DD);    // idx = row*64 + o

    // ---- issue A loads (4 int4/thread) and B-half0 loads (16 int4/thread)
    int ao = t & 63;                 // A octet (fixed per thread), rows t>>6 + 4s
    int bo = t & 31;                 // B octet (fixed), classes t>>5 + 8s
    int4 a0 = gA[((t >> 6) + 0)  * 64 + ao];
    int4 a1 = gA[((t >> 6) + 4)  * 64 + ao];
    int4 a2 = gA[((t >> 6) + 8)  * 64 + ao];
    int4 a3 = gA[((t >> 6) + 12) * 64 + ao];
    int4 br[16];
    #pragma unroll
    for (int s = 0; s < 16; ++s)
        br[s] = gB[((t >> 5) + 8 * s) * 64 + bo];
    // ---- write A (swizzled)
    {
        int r;
        r = (t >> 6) + 0;  *(int4*)&As[r * 1024 + ((ao * 16) ^ ((r & 7) << 4))] = a0;
        r = (t >> 6) + 4;  *(int4*)&As[r * 1024 + ((ao * 16) ^ ((r & 7) << 4))] = a1;
        r = (t >> 6) + 8;  *(int4*)&As[r * 1024 + ((ao * 16) ^ ((r & 7) << 4))] = a2;
        r = (t >> 6) + 12; *(int4*)&As[r * 1024 + ((ao * 16) ^ ((r & 7) << 4))] = a3;
    }
    // ---- write B half0 (swizzled)
    #pragma unroll
    for (int s = 0; s < 16; ++s) {
        int c = (t >> 5) + 8 * s;
        *(int4*)&Bs[c * 512 + ((bo * 16) ^ ((c & 7) << 4))] = br[s];
    }
    __syncthreads();
    // ---- issue B half1 loads now; they complete under compute of half 0
    #pragma unroll
    for (int s = 0; s < 16; ++s)
        br[s] = gB[((t >> 5) + 8 * s) * 64 + 32 + bo];

    f32x4 acc[2];
    acc[0] = (f32x4){0.f, 0.f, 0.f, 0.f};
    acc[1] = (f32x4){0.f, 0.f, 0.f, 0.f};
    int arow = l & 15, kq = l >> 4;
    int c0 = 32 * w;
    int aswz = (arow & 7) << 4;
    int cA = c0 + arow, cB = c0 + 16 + arow;
    int aoffA = cA * 512, aswzA = (cA & 7) << 4;
    int aoffB = cB * 512, aswzB = (cB & 7) << 4;

    // ---- compute half 0 (K = 0..255, 8 chunks of 32)
    #pragma unroll
    for (int ch = 0; ch < 8; ++ch) {
        int kb = ch * 64 + kq * 16;
        bf16x8 af = *(const bf16x8*)&As[arow * 1024 + (kb ^ aswz)];
        bf16x8 b0 = *(const bf16x8*)&Bs[aoffA + (kb ^ aswzA)];
        bf16x8 b1 = *(const bf16x8*)&Bs[aoffB + (kb ^ aswzB)];
        acc[0] = __builtin_amdgcn_mfma_f32_16x16x32_bf16(af, b0, acc[0], 0, 0, 0);
        acc[1] = __builtin_amdgcn_mfma_f32_16x16x32_bf16(af, b1, acc[1], 0, 0, 0);
    }
    __syncthreads();   // everyone done reading Bs half0
    // ---- write B half1
    #pragma unroll
    for (int s = 0; s < 16; ++s) {
        int c = (t >> 5) + 8 * s;
        *(int4*)&Bs[c * 512 + ((bo * 16) ^ ((c & 7) << 4))] = br[s];
    }
    __syncthreads();
    // ---- compute half 1 (K = 256..511; A byte offset +512)
    #pragma unroll
    for (int ch = 0; ch < 8; ++ch) {
        int kb = ch * 64 + kq * 16;
        bf16x8 af = *(const bf16x8*)&As[arow * 1024 + ((512 + kb) ^ aswz)];
        bf16x8 b0 = *(const bf16x8*)&Bs[aoffA + (kb ^ aswzA)];
        bf16x8 b1 = *(const bf16x8*)&Bs[aoffB + (kb ^ aswzB)];
        acc[0] = __builtin_amdgcn_mfma_f32_16x16x32_bf16(af, b0, acc[0], 0, 0, 0);
        acc[1] = __builtin_amdgcn_mfma_f32_16x16x32_bf16(af, b1, acc[1], 0, 0, 0);
    }

    // ---- epilogue: S per row = sum over all 128 classes (cross-wave reduce)
    float rsum[4];
    #pragma unroll
    for (int r = 0; r < 4; ++r) {
        float s = acc[0][r] + acc[1][r];
        #pragma unroll
        for (int o = 1; o < 16; o <<= 1) s += __shfl_xor(s, o);
        rsum[r] = s;
    }
    if ((l & 15) == 0) {
        #pragma unroll
        for (int r = 0; r < 4; ++r) part[w][kq * 4 + r] = rsum[r];
    }
    __syncthreads();
    if (t < MT) Ss[t] = part[0][t] + part[1][t] + part[2][t] + part[3][t];
    __syncthreads();
    float p = 0.f;
    #pragma unroll
    for (int f = 0; f < 2; ++f) {
        float cf = cnts[c0 + f * 16 + (l & 15)];
        float e = 0.f;
        #pragma unroll
        for (int r = 0; r < 4; ++r) e += __expf(Ss[kq * 4 + r] - acc[f][r]);
        p += cf * e;
    }
    #pragma unroll
    for (int o = 32; o >= 1; o >>= 1) p += __shfl_xor(p, o);
    if (l == 0) wred[w] = p;
    __syncthreads();
    if (t == 0) {
        atomicAdd(ws + NEG_OFF, wred[0] + wred[1] + wred[2] + wred[3]);
        __threadfence();
        int old = atomicAdd((int*)ws + DONE_OFF, 1);
        sdone = (old == NB2 - 1);
        if (sdone) sneg = atomicAdd(ws + NEG_OFF, 0.0f);  // coherent read-back
    }
    __syncthreads();
    if (sdone) {
        float neg = sneg;
        float s = 0.f;
        for (int i = t; i < NN; i += 256) {
            float dv = ws[D_OFF + i];
            s += logf(__expf(dv) + neg) - dv;
        }
        #pragma unroll
        for (int o = 32; o >= 1; o >>= 1) s += __shfl_xor(s, o);
        __syncthreads();
        if (l == 0) wred[w] = s;
        __syncthreads();
        if (t == 0) out[0] = wred[0] + wred[1] + wred[2] + wred[3];
    }
}

extern "C" void kernel_launch(void* const* d_in, const int* in_sizes, int n_in,
                              void* d_out, int out_size, void* d_ws, size_t ws_size,
                              hipStream_t stream) {
    const float* img  = (const float*)d_in[0];
    const float* txt  = (const float*)d_in[1];
    const int* labels = (const int*)d_in[2];
    float* ws  = (float*)d_ws;
    float* out = (float*)d_out;

    k1_rows<<<NN / 4, 256, 0, stream>>>(img, txt, ws);
    k1b_gather<<<CP, 512, 0, stream>>>(img, labels, ws);
    k2_neg<<<NB2, 256, 0, stream>>>(ws, out);
}